// Round 1
// baseline (103.701 us; speedup 1.0000x reference)
//
#include <hip/hip_runtime.h>
#include <float.h>

#define B 8
#define L 512
#define D 128
#define U 32
#define WIN 128
#define EPS 1e-7f

// Kernel 1: fold the additive-attention projection into two D-vectors + scalar.
// wq[d] = sum_u Wt[d,u]*Wa[u]; wk[d] = sum_u Wx[d,u]*Wa[u]; c = Wa.bh + ba
__global__ void prep_kernel(const float* __restrict__ Wt, const float* __restrict__ Wx,
                            const float* __restrict__ bh, const float* __restrict__ Wa,
                            const float* __restrict__ ba, float* __restrict__ wq,
                            float* __restrict__ wk, float* __restrict__ cc) {
    int d = threadIdx.x;  // 0..127
    float sq = 0.f, sk = 0.f;
#pragma unroll
    for (int u = 0; u < U; ++u) {
        float wa = Wa[u];
        sq += Wt[d * U + u] * wa;
        sk += Wx[d * U + u] * wa;
    }
    wq[d] = sq;
    wk[d] = sk;
    if (d == 0) {
        float s = ba[0];
        for (int u = 0; u < U; ++u) s += bh[u] * Wa[u];
        *cc = s;
    }
}

// Kernel 2: scalar scores per position: qd[r] = x_row . wq ; kd[r] = x_row . wk
__global__ void scores_kernel(const float* __restrict__ x, const float* __restrict__ wq,
                              const float* __restrict__ wk, float* __restrict__ qd,
                              float* __restrict__ kd) {
    __shared__ float swq[D], swk[D];
    int tid = threadIdx.x;
    if (tid < D) { swq[tid] = wq[tid]; swk[tid] = wk[tid]; }
    __syncthreads();
    int r = blockIdx.x * blockDim.x + tid;  // row in [0, B*L)
    const float* row = x + (size_t)r * D;
    float sq = 0.f, sk = 0.f;
#pragma unroll 4
    for (int d = 0; d < D; ++d) {
        float v = row[d];
        sq += v * swq[d];
        sk += v * swk[d];
    }
    qd[r] = sq;
    kd[r] = sk;
}

// Kernel 3: per-batch column sums xsum[b,d] = sum_s x[b,s,d]
__global__ void xsum_kernel(const float* __restrict__ x, float* __restrict__ xsum) {
    int b = blockIdx.x, d = threadIdx.x;
    const float* xb = x + (size_t)b * L * D + d;
    float s = 0.f;
#pragma unroll 8
    for (int i = 0; i < L; ++i) s += xb[(size_t)i * D];
    xsum[b * D + d] = s;
}

// Kernel 4: one block per (b,t). Thread d owns output dim d.
// Masked (outside-window) keys carry weight w0 = exp(-m) each (mask zeroes
// scores, does NOT -inf them). m = max(0, window max) since zeros always exist.
__global__ void attn_kernel(const float* __restrict__ x, const float* __restrict__ qd,
                            const float* __restrict__ kd, const float* __restrict__ cc,
                            const float* __restrict__ xsum, float* __restrict__ out) {
    __shared__ float w[WIN];
    __shared__ float red[WIN];
    int bidx = blockIdx.x;
    int b = bidx / L, t = bidx % L;
    int tid = threadIdx.x;  // 0..127
    int s0 = t - (WIN / 2 - 1); if (s0 < 0) s0 = 0;
    int s1 = t + WIN / 2 + 1;   if (s1 > L) s1 = L;
    int count = s1 - s0;
    float qdt = qd[b * L + t] + *cc;
    float e = (tid < count) ? (qdt + kd[b * L + s0 + tid]) : -FLT_MAX;

    // block-wide max over the window
    red[tid] = e;
    __syncthreads();
    for (int off = 64; off > 0; off >>= 1) {
        if (tid < off) red[tid] = fmaxf(red[tid], red[tid + off]);
        __syncthreads();
    }
    float m = fmaxf(red[0], 0.f);  // zeros outside window always present
    __syncthreads();

    float w0 = __expf(-m);                              // weight of each masked key
    float wv = (tid < count) ? __expf(e - m) : 0.f;
    w[tid] = wv - w0;  // pre-subtract so inner loop is a pure FMA
    red[tid] = wv;
    __syncthreads();
    for (int off = 64; off > 0; off >>= 1) {
        if (tid < off) red[tid] += red[tid + off];
        __syncthreads();
    }
    float denom = red[0] + (float)(L - count) * w0 + EPS;
    float inv = 1.f / denom;

    const float* xb = x + ((size_t)(b * L + s0)) * D + tid;
    float acc = 0.f;
    for (int k = 0; k < count; ++k) {
        acc += w[k] * xb[(size_t)k * D];
    }
    acc += w0 * xsum[b * D + tid];
    out[(size_t)bidx * D + tid] = acc * inv;
}

extern "C" void kernel_launch(void* const* d_in, const int* in_sizes, int n_in,
                              void* d_out, int out_size, void* d_ws, size_t ws_size,
                              hipStream_t stream) {
    const float* x  = (const float*)d_in[0];
    const float* Wt = (const float*)d_in[1];
    const float* Wx = (const float*)d_in[2];
    const float* bh = (const float*)d_in[3];
    const float* Wa = (const float*)d_in[4];
    const float* ba = (const float*)d_in[5];
    float* out = (float*)d_out;

    float* ws   = (float*)d_ws;
    float* wq   = ws;              // 128
    float* wk   = wq + D;          // 128
    float* cc   = wk + D;          // 1 (+3 pad)
    float* qd   = cc + 4;          // B*L = 4096
    float* kd   = qd + B * L;      // 4096
    float* xsum = kd + B * L;      // B*D = 1024

    prep_kernel<<<1, D, 0, stream>>>(Wt, Wx, bh, Wa, ba, wq, wk, cc);
    scores_kernel<<<(B * L) / 256, 256, 0, stream>>>(x, wq, wk, qd, kd);
    xsum_kernel<<<B, D, 0, stream>>>(x, xsum);
    attn_kernel<<<B * L, D, 0, stream>>>(x, qd, kd, cc, xsum, out);
}

// Round 2
// 93.068 us; speedup vs baseline: 1.1142x; 1.1142x over previous
//
#include <hip/hip_runtime.h>
#include <float.h>

#define B 8
#define L 512
#define D 128
#define U 32
#define WIN 128
#define EPS 1e-7f
#define T 8                      // queries per attn block
#define ROWS (T + WIN - 1)       // 135 key-rows touched per block
#define WPITCH (WIN + T)         // 136 (w row pitch)

// Kernel 1 (fused pre): per-row scalar scores + per-slab column-sum partials.
//   qd[r] = x_row . (Wt@Wa) + (Wa.bh + ba)   (c folded in)
//   kd[r] = x_row . (Wx@Wa)
//   xpart[blk][d] = sum over this block's 256 rows of x[.,d]
__global__ __launch_bounds__(256) void pre_kernel(
        const float* __restrict__ x, const float* __restrict__ Wt,
        const float* __restrict__ Wx, const float* __restrict__ bh,
        const float* __restrict__ Wa, const float* __restrict__ ba,
        float* __restrict__ qd, float* __restrict__ kd,
        float* __restrict__ xpart) {
    __shared__ float swq[D], swk[D];
    __shared__ float scc;
    __shared__ float red[256];
    int blk = blockIdx.x, tid = threadIdx.x;

    if (tid < D) {
        float sq = 0.f, sk = 0.f;
#pragma unroll
        for (int u = 0; u < U; ++u) {
            float wa = Wa[u];
            sq += Wt[tid * U + u] * wa;
            sk += Wx[tid * U + u] * wa;
        }
        swq[tid] = sq; swk[tid] = sk;
    }
    if (tid == 0) {
        float s = ba[0];
        for (int u = 0; u < U; ++u) s += bh[u] * Wa[u];
        scc = s;
    }
    __syncthreads();

    // scalar scores: one row per thread, float4 streaming dot
    int r = blk * 256 + tid;
    const float4* xr = (const float4*)(x + (size_t)r * D);
    float sq = 0.f, sk = 0.f;
#pragma unroll
    for (int i = 0; i < D / 4; ++i) {
        float4 v = xr[i];
        sq += v.x * swq[4*i] + v.y * swq[4*i+1] + v.z * swq[4*i+2] + v.w * swq[4*i+3];
        sk += v.x * swk[4*i] + v.y * swk[4*i+1] + v.z * swk[4*i+2] + v.w * swk[4*i+3];
    }
    qd[r] = sq + scc;
    kd[r] = sk;

    // column-sum partial over this block's 256-row slab (coalesced)
    int d = tid & (D - 1), h = tid >> 7;   // 2 halves of 128 rows
    const float* xp = x + ((size_t)(blk * 256 + h * 128)) * D + d;
    float s = 0.f;
#pragma unroll 8
    for (int i = 0; i < 128; ++i) s += xp[(size_t)i * D];
    red[tid] = s;
    __syncthreads();
    if (tid < 128) xpart[blk * 128 + tid] = red[tid] + red[tid + 128];
}

// Kernel 2: one block per 8 consecutive queries. Thread = (q, dt):
// q = tid>>5 owns query t0+q; dt = tid&31 owns dims 4*dt..4*dt+3.
// Masked-key handling: mask zeroes scores (not -inf) => each out-of-window key
// carries weight w0 = exp(-m); folded exactly via w0 * xsum_batch.
__global__ __launch_bounds__(256) void attn_kernel(
        const float* __restrict__ x, const float* __restrict__ qd,
        const float* __restrict__ kd, const float* __restrict__ xpart,
        float* __restrict__ out) {
    __shared__ float w[T][WPITCH];
    __shared__ float adj[T];
    int blk = blockIdx.x;
    int b = blk >> 6;                 // 64 tiles per batch
    int t0 = (blk & 63) * T;
    int row0 = t0 - (WIN / 2 - 1);    // t0 - 63
    int tid = threadIdx.x;
    int q = tid >> 5;
    int dt = tid & 31;

    // zero the weight tile
    for (int i = tid; i < T * WPITCH; i += 256) ((float*)w)[i] = 0.f;
    __syncthreads();

    // ---- weight phase: lanes (q, kt) handle keys kt, kt+32, kt+64, kt+96 ----
    int kt = dt;
    int t = t0 + q;
    float qv = qd[b * L + t];
    float e[4];
    int   sv[4];
#pragma unroll
    for (int i = 0; i < 4; ++i) {
        int k = kt + 32 * i;
        int s = t - 63 + k;
        bool valid = ((unsigned)s < (unsigned)L);
        sv[i] = valid;
        e[i] = valid ? (qv + kd[b * L + s]) : -FLT_MAX;
    }
    float mx = fmaxf(fmaxf(e[0], e[1]), fmaxf(e[2], e[3]));
#pragma unroll
    for (int off = 16; off > 0; off >>= 1) mx = fmaxf(mx, __shfl_xor(mx, off));
    float m = fmaxf(mx, 0.f);          // masked zeros always present (WIN < L)
    float w0 = __expf(-m);
    float wv[4], sm = 0.f;
#pragma unroll
    for (int i = 0; i < 4; ++i) {
        wv[i] = sv[i] ? __expf(e[i] - m) : 0.f;
        sm += wv[i];
    }
#pragma unroll
    for (int off = 16; off > 0; off >>= 1) sm += __shfl_xor(sm, off);
    int ss0 = max(0, t - 63), ss1 = min(L, t + 64);
    int count = ss1 - ss0;
    float denom = sm + (float)(L - count) * w0 + EPS;
    float inv = 1.f / denom;
#pragma unroll
    for (int i = 0; i < 4; ++i) {
        int k = kt + 32 * i;
        if (sv[i]) w[q][q + k] = (wv[i] - w0) * inv;   // pre-subtract w0
    }
    if (kt == 0) adj[q] = w0 * inv;
    __syncthreads();

    // ---- PV phase: stream 135 rows, float4 per thread ----
    float4 acc = {0.f, 0.f, 0.f, 0.f};
    const float4* xb = (const float4*)(x + (size_t)b * L * D);
#pragma unroll 4
    for (int r = 0; r < ROWS; ++r) {
        int s = row0 + r;
        int sc = min(max(s, 0), L - 1);       // clamped; weight is 0 when clamped
        float4 xv = xb[(size_t)sc * (D / 4) + dt];
        float ww = w[q][r];
        acc.x += ww * xv.x; acc.y += ww * xv.y;
        acc.z += ww * xv.z; acc.w += ww * xv.w;
    }

    // epilogue: add w0 * xsum_batch, write out
    const float4* xp0 = (const float4*)(xpart + (size_t)(2 * b) * D);
    const float4* xp1 = (const float4*)(xpart + (size_t)(2 * b + 1) * D);
    float4 s0 = xp0[dt], s1 = xp1[dt];
    float a = adj[q];
    float4 o;
    o.x = acc.x + a * (s0.x + s1.x);
    o.y = acc.y + a * (s0.y + s1.y);
    o.z = acc.z + a * (s0.z + s1.z);
    o.w = acc.w + a * (s0.w + s1.w);
    ((float4*)out)[((size_t)(b * L + t)) * (D / 4) + dt] = o;
}

extern "C" void kernel_launch(void* const* d_in, const int* in_sizes, int n_in,
                              void* d_out, int out_size, void* d_ws, size_t ws_size,
                              hipStream_t stream) {
    const float* x  = (const float*)d_in[0];
    const float* Wt = (const float*)d_in[1];
    const float* Wx = (const float*)d_in[2];
    const float* bh = (const float*)d_in[3];
    const float* Wa = (const float*)d_in[4];
    const float* ba = (const float*)d_in[5];
    float* out = (float*)d_out;

    float* ws    = (float*)d_ws;
    float* qd    = ws;                  // B*L = 4096 (c folded in)
    float* kd    = qd + B * L;          // 4096
    float* xpart = kd + B * L;          // 16 * 128 = 2048

    pre_kernel<<<(B * L) / 256, 256, 0, stream>>>(x, Wt, Wx, bh, Wa, ba, qd, kd, xpart);
    attn_kernel<<<B * (L / T), 256, 0, stream>>>(x, qd, kd, xpart, out);
}

// Round 3
// 79.615 us; speedup vs baseline: 1.3025x; 1.1690x over previous
//
#include <hip/hip_runtime.h>
#include <float.h>

#define B 8
#define L 512
#define D 128
#define U 32
#define WIN 128
#define EPS 1e-7f
#define T 8                      // queries per attn block
#define ROWS (T + WIN - 1)       // 135 key-rows touched per block
#define WPITCH 10                // w[r][q] pitch: even (float2-aligned), 2-way-bank only

// ---------------- pre: scores + column-sum partials ----------------
// 32 blocks x 256 threads; block handles a 128-row slab.
// scores: 2 threads per row (64-dim halves), LDS combine.
// colsum: thread = (col, half-of-rows), 64 loads, LDS combine.
__global__ __launch_bounds__(256) void pre_kernel(
        const float* __restrict__ x, const float* __restrict__ Wt,
        const float* __restrict__ Wx, const float* __restrict__ bh,
        const float* __restrict__ Wa, const float* __restrict__ ba,
        float* __restrict__ qd, float* __restrict__ kd,
        float* __restrict__ xpart) {
    __shared__ float swq[D], swk[D];
    __shared__ float scc;
    __shared__ float redq[256], redk[256];
    int blk = blockIdx.x, tid = threadIdx.x;
    int r0 = blk * 128;

    if (tid < D) {
        float sq = 0.f, sk = 0.f;
#pragma unroll
        for (int u = 0; u < U; ++u) {
            float wa = Wa[u];
            sq += Wt[tid * U + u] * wa;
            sk += Wx[tid * U + u] * wa;
        }
        swq[tid] = sq; swk[tid] = sk;
    }
    if (tid == 0) {
        float s = ba[0];
        for (int u = 0; u < U; ++u) s += bh[u] * Wa[u];
        scc = s;
    }
    __syncthreads();

    // scores: row = r0 + (tid&127), half h = tid>>7 covers dims [64h, 64h+64)
    {
        int rr = tid & 127, h = tid >> 7;
        const float4* xr = (const float4*)(x + ((size_t)(r0 + rr)) * D + h * 64);
        float sq = 0.f, sk = 0.f;
        int d0 = h * 64;
#pragma unroll
        for (int i = 0; i < 16; ++i) {
            float4 v = xr[i];
            sq += v.x * swq[d0 + 4*i]     + v.y * swq[d0 + 4*i + 1]
                + v.z * swq[d0 + 4*i + 2] + v.w * swq[d0 + 4*i + 3];
            sk += v.x * swk[d0 + 4*i]     + v.y * swk[d0 + 4*i + 1]
                + v.z * swk[d0 + 4*i + 2] + v.w * swk[d0 + 4*i + 3];
        }
        redq[tid] = sq; redk[tid] = sk;
    }
    __syncthreads();
    if (tid < 128) {
        qd[r0 + tid] = redq[tid] + redq[tid + 128] + scc;
        kd[r0 + tid] = redk[tid] + redk[tid + 128];
    }
    __syncthreads();

    // colsum: col d = tid&127, half h = tid>>7 covers rows [r0+64h, +64)
    {
        int d = tid & 127, h = tid >> 7;
        const float* xp = x + ((size_t)(r0 + h * 64)) * D + d;
        float s = 0.f;
#pragma unroll 8
        for (int i = 0; i < 64; ++i) s += xp[(size_t)i * D];
        redq[tid] = s;
    }
    __syncthreads();
    if (tid < 128) xpart[blk * 128 + tid] = redq[tid] + redq[tid + 128];
}

// ---------------- attn: one block per 8 queries ----------------
// Weight phase: thread (ql, kt) = (tid>>5, tid&31) covers keys kt+32i of query ql.
// PV phase: thread (g, h, dt) = (tid>>6, (tid>>5)&1, tid&31):
//   group g owns queries 2g, 2g+1 (register-blocked), h splits the row range,
//   dt owns dims 4dt..4dt+3; halves combine via __shfl_xor(...,32) (same wave).
// Mask zeroes scores (not -inf): every out-of-window key weighs w0 = exp(-m);
// folded exactly as w0 * xsum_batch with in-window weights pre-subtracted.
__global__ __launch_bounds__(256) void attn_kernel(
        const float* __restrict__ x, const float* __restrict__ qd,
        const float* __restrict__ kd, const float* __restrict__ xpart,
        float* __restrict__ out) {
    __shared__ float w[ROWS * WPITCH];
    __shared__ float adj[T];
    int blk = blockIdx.x;
    int b = blk >> 6;                 // 64 tiles per batch
    int t0 = (blk & 63) * T;
    int row0 = t0 - (WIN / 2 - 1);    // t0 - 63
    int tid = threadIdx.x;

    for (int i = tid; i < ROWS * WPITCH; i += 256) w[i] = 0.f;
    __syncthreads();

    // ---- weight phase ----
    {
        int ql = tid >> 5, kt = tid & 31;
        int t = t0 + ql;
        float qv = qd[b * L + t];
        float e[4];
        int   sv[4];
#pragma unroll
        for (int i = 0; i < 4; ++i) {
            int k = kt + 32 * i;
            int s = t - 63 + k;
            bool valid = ((unsigned)s < (unsigned)L);
            sv[i] = valid;
            e[i] = valid ? (qv + kd[b * L + s]) : -FLT_MAX;
        }
        float mx = fmaxf(fmaxf(e[0], e[1]), fmaxf(e[2], e[3]));
#pragma unroll
        for (int off = 16; off > 0; off >>= 1) mx = fmaxf(mx, __shfl_xor(mx, off));
        float m = fmaxf(mx, 0.f);          // masked zeros always present (WIN < L)
        float w0 = __expf(-m);
        float wv[4], sm = 0.f;
#pragma unroll
        for (int i = 0; i < 4; ++i) {
            wv[i] = sv[i] ? __expf(e[i] - m) : 0.f;
            sm += wv[i];
        }
#pragma unroll
        for (int off = 16; off > 0; off >>= 1) sm += __shfl_xor(sm, off);
        int ss0 = max(0, t - 63), ss1 = min(L, t + 65);
        int count = ss1 - ss0;
        float inv = 1.f / (sm + (float)(L - count) * w0 + EPS);
#pragma unroll
        for (int i = 0; i < 4; ++i) {
            int k = kt + 32 * i;
            if (sv[i]) w[(ql + k) * WPITCH + ql] = (wv[i] - w0) * inv;
        }
        if (kt == 0) adj[ql] = w0 * inv;
    }
    __syncthreads();

    // ---- PV phase ----
    int dt = tid & 31, h = (tid >> 5) & 1, g = tid >> 6;
    int rlo = max(0, -row0);
    int rhi = min(ROWS, L - row0);
    int mid = rlo + ((rhi - rlo + 1) >> 1);
    int ra = h ? mid : rlo;
    int rb = h ? rhi : mid;

    float4 accA = {0.f, 0.f, 0.f, 0.f};
    float4 accB = {0.f, 0.f, 0.f, 0.f};
    const float4* xb = (const float4*)(x + (size_t)b * L * D);
#pragma unroll 4
    for (int r = ra; r < rb; ++r) {
        int s = row0 + r;
        float4 xv = xb[(size_t)s * (D / 4) + dt];
        float2 wp = *(const float2*)&w[r * WPITCH + 2 * g];
        accA.x += wp.x * xv.x; accA.y += wp.x * xv.y;
        accA.z += wp.x * xv.z; accA.w += wp.x * xv.w;
        accB.x += wp.y * xv.x; accB.y += wp.y * xv.y;
        accB.z += wp.y * xv.z; accB.w += wp.y * xv.w;
    }
    // combine row-halves: partner is lane^32 (same wave)
    accA.x += __shfl_xor(accA.x, 32); accA.y += __shfl_xor(accA.y, 32);
    accA.z += __shfl_xor(accA.z, 32); accA.w += __shfl_xor(accA.w, 32);
    accB.x += __shfl_xor(accB.x, 32); accB.y += __shfl_xor(accB.y, 32);
    accB.z += __shfl_xor(accB.z, 32); accB.w += __shfl_xor(accB.w, 32);

    if (h == 0) {
        // batch xsum from 4 slab partials
        const float4* xp = (const float4*)(xpart + (size_t)(4 * b) * D);
        float4 s0 = xp[dt], s1 = xp[32 + dt], s2 = xp[64 + dt], s3 = xp[96 + dt];
        float sx = s0.x + s1.x + s2.x + s3.x;
        float sy = s0.y + s1.y + s2.y + s3.y;
        float sz = s0.z + s1.z + s2.z + s3.z;
        float sw = s0.w + s1.w + s2.w + s3.w;
        float aA = adj[2 * g], aB = adj[2 * g + 1];
        float4 oA = {accA.x + aA * sx, accA.y + aA * sy, accA.z + aA * sz, accA.w + aA * sw};
        float4 oB = {accB.x + aB * sx, accB.y + aB * sy, accB.z + aB * sz, accB.w + aB * sw};
        float4* ob = (float4*)out;
        ob[((size_t)(b * L + t0 + 2 * g))     * (D / 4) + dt] = oA;
        ob[((size_t)(b * L + t0 + 2 * g + 1)) * (D / 4) + dt] = oB;
    }
}

extern "C" void kernel_launch(void* const* d_in, const int* in_sizes, int n_in,
                              void* d_out, int out_size, void* d_ws, size_t ws_size,
                              hipStream_t stream) {
    const float* x  = (const float*)d_in[0];
    const float* Wt = (const float*)d_in[1];
    const float* Wx = (const float*)d_in[2];
    const float* bh = (const float*)d_in[3];
    const float* Wa = (const float*)d_in[4];
    const float* ba = (const float*)d_in[5];
    float* out = (float*)d_out;

    float* ws    = (float*)d_ws;
    float* qd    = ws;                  // B*L = 4096 (c folded in)
    float* kd    = qd + B * L;          // 4096
    float* xpart = kd + B * L;          // 32 * 128 = 4096

    pre_kernel<<<32, 256, 0, stream>>>(x, Wt, Wx, bh, Wa, ba, qd, kd, xpart);
    attn_kernel<<<B * (L / T), 256, 0, stream>>>(x, qd, kd, xpart, out);
}